// Round 5
// baseline (266.351 us; speedup 1.0000x reference)
//
#include <hip/hip_runtime.h>
#include <hip/hip_fp16.h>

// Bilateral denoiser, 1080x1920x11 fp32 -> 1080x1920x3 fp32.
// d^2 <= 36 (113 taps; pruning error ~5e-3 — R2=25 and exp-approx pow both
// FAIL due to 1/EPS=1e4 amplification in the epilogue ratio; keep exact
// c^128 via 7 squarings).  PY=4 y-stacked px/thread as two f2 pk-pairs share
// every LDS tap read (b128 nrm+z, b64 fp16 col). Per-(j,dx,p) constants
// {-log2e/dist, -log2e/2*d^2} from wave-uniform constant table; inactive
// combos carry lwK=-1e30 -> w=0 (no per-p branches).
// Tile 32x32, block (32,8), LDS 46.5KB -> 3 blocks/CU (12 waves).

namespace {
constexpr int IMG_H = 1080;
constexpr int IMG_W = 1920;
constexpr int CHN   = 11;
constexpr int TLX   = 32;
constexpr int TLY   = 32;
constexpr int HALO  = 6;
constexpr int RX    = TLX + 2 * HALO;   // 44
constexpr int RY    = TLY + 2 * HALO;   // 44
constexpr int PY    = 4;
constexpr int R2MAX = 36;

constexpr double CD = -1.4426950408889634;   // -log2(e)

struct alignas(16) Tab {
    // [j+6][dx+6] -> {invdC p0..p3, lwK p0..p3}; dy_p = j - p
    float v[16][13][8];
    constexpr Tab() : v{} {
        for (int jj = 0; jj < 16; ++jj)
            for (int di = 0; di < 13; ++di)
                for (int p = 0; p < 4; ++p) {
                    const int dy = (jj - 6) - p, dx = di - 6;
                    const int d2 = dy * dy + dx * dx;
                    float ic, lwk;
                    if (d2 == 0) {            // center: ad==0; huge ic -> clamp
                        ic = -1e30f; lwk = 0.f;
                    } else if (d2 <= R2MAX) { // active tap
                        double s = (double)d2, x = s;
                        for (int it = 0; it < 60; ++it) x = 0.5 * (x + s / x);
                        ic  = (float)(CD / x);
                        lwk = (float)(0.5 * CD * d2);
                    } else {                  // pruned / out of window: w -> 0
                        ic = (float)CD; lwk = -1e30f;
                    }
                    v[jj][di][p]     = ic;
                    v[jj][di][4 + p] = lwk;
                }
    }
};
}
__constant__ Tab TAB;

typedef float f2 __attribute__((ext_vector_type(2)));

__global__ __launch_bounds__(256, 3)
void bilateral_denoise_kernel(const float* __restrict__ in, float* __restrict__ out) {
    __shared__ float4  ldsA[RY * RX];       // {nrm0, nrm1, nrm2, z}   16 B
    __shared__ __half2 ldsC[RY * RX][2];    // {col01, col2_}           8 B

    const int lx  = threadIdx.x;
    const int ty  = threadIdx.y;
    const int bx0 = blockIdx.x * TLX;
    const int by0 = blockIdx.y * TLY;
    const int tid = ty * 32 + lx;

    // ---- stage tile + halo (OOB -> zeros => dot=0 => c^128=0 => w=0) ----
    for (int r = tid; r < RY * RX; r += 256) {
        const int ry = r / RX;
        const int rx = r - ry * RX;
        const int gy = by0 - HALO + ry;
        const int gx = bx0 - HALO + rx;
        float4 A = make_float4(0.f, 0.f, 0.f, 0.f);
        float c0 = 0.f, c1 = 0.f, c2 = 0.f;
        if ((unsigned)gy < (unsigned)IMG_H && (unsigned)gx < (unsigned)IMG_W) {
            const float* p = in + (gy * IMG_W + gx) * CHN;
            c0 = p[0]; c1 = p[1]; c2 = p[2];
            A.x = p[3]; A.y = p[4]; A.z = p[5]; A.w = p[9];
        }
        ldsA[r] = A;
        ldsC[r][0] = __floats2half2_rn(c0, c1);
        ldsC[r][1] = __floats2half2_rn(c2, 0.f);
    }
    __syncthreads();

    // ---- per-thread center state: 4 px packed as two f2 pairs ----
    const int gx = bx0 + lx;
    const int crow = (ty * PY + HALO) * RX + HALO + lx;
    const float4 A0 = ldsA[crow];
    const float4 A1 = ldsA[crow + RX];
    const float4 A2 = ldsA[crow + 2 * RX];
    const float4 A3 = ldsA[crow + 3 * RX];
    const f2 cnx01 = {A0.x, A1.x}, cnx23 = {A2.x, A3.x};
    const f2 cny01 = {A0.y, A1.y}, cny23 = {A2.y, A3.y};
    const f2 cnz01 = {A0.z, A1.z}, cnz23 = {A2.z, A3.z};
    const f2 cz01  = {A0.w, A1.w}, cz23  = {A2.w, A3.w};
    f2 rdz01, rdz23;
#pragma unroll
    for (int p = 0; p < PY; ++p) {
        const int gy = by0 + ty * PY + p;
        float dzv = 0.f;
        if (gy < IMG_H) dzv = in[(gy * IMG_W + gx) * CHN + 10];
        // dz<=0 -> rcp(0)=+inf -> rrc=-inf -> clamped to CD/EPS == 1/max(.,EPS)
        const float rv = __builtin_amdgcn_rcpf(fmaxf(dzv, 0.f));
        if (p == 0) rdz01.x = rv;
        else if (p == 1) rdz01.y = rv;
        else if (p == 2) rdz23.x = rv;
        else rdz23.y = rv;
    }
    f2 ax01 = (f2)(0.f), ay01 = (f2)(0.f), az01 = (f2)(0.f), aw01 = (f2)(0.f);
    f2 ax23 = (f2)(0.f), ay23 = (f2)(0.f), az23 = (f2)(0.f), aw23 = (f2)(0.f);

    const float RCLAMP = -14426.9504f;   // CD * 1e4 (== CD/EPS)

    // j = dy + p; all gating wave-uniform (j, dx loop counters).
#pragma unroll 1
    for (int j = -HALO; j <= HALO + PY - 1; ++j) {   // 16 rows
        const int dymin = j < 0 ? -j : (j > PY - 1 ? j - (PY - 1) : 0);
        const int m = R2MAX - dymin * dymin;
        const int rowb = (ty * PY + HALO + j) * RX + HALO + lx;
        const float* trow = &TAB.v[j + 6][0][0];
#pragma unroll
        for (int dxi = 0; dxi < 13; ++dxi) {
            const int dx = dxi - 6;
            if (dx * dx <= m) {                       // uniform scalar branch
                const float4 T0 = *(const float4*)(trow + dxi * 8);      // s_load
                const float4 T1 = *(const float4*)(trow + dxi * 8 + 4);
                const f2 ic01 = {T0.x, T0.y}, ic23 = {T0.z, T0.w};
                const f2 lw01 = {T1.x, T1.y}, lw23 = {T1.z, T1.w};
                const float4 A = ldsA[rowb + dx];                        // b128
                const __half2 h01 = ldsC[rowb + dx][0];                  // b64
                const __half2 h2x = ldsC[rowb + dx][1];
                const float c0 = __low2float(h01);
                const float c1 = __high2float(h01);
                const float c2 = __low2float(h2x);
                // ---- pair 0/1 ----
                {
                    const f2 dz  = (f2)(A.w) - cz01;
                    const f2 dot = (f2)(A.x) * cnx01 + ((f2)(A.y) * cny01 + (f2)(A.z) * cnz01);
                    f2 c = __builtin_elementwise_max(dot, (f2)(0.f));
                    c = __builtin_elementwise_min(c, (f2)(1.f));
                    f2 s = c * c;                     // c^128: 7 pk_mul (exact)
                    s = s * s; s = s * s; s = s * s;
                    s = s * s; s = s * s; s = s * s;
                    const f2 r   = __builtin_elementwise_max(ic01 * rdz01, (f2)(RCLAMP));
                    const f2 ad  = __builtin_elementwise_abs(dz);
                    const f2 arg = ad * r + lw01;
                    f2 w;
                    w.x = __builtin_amdgcn_exp2f(arg.x);
                    w.y = __builtin_amdgcn_exp2f(arg.y);
                    w *= s;
                    ax01 = (f2)(c0) * w + ax01;
                    ay01 = (f2)(c1) * w + ay01;
                    az01 = (f2)(c2) * w + az01;
                    aw01 += w;
                }
                // ---- pair 2/3 ----
                {
                    const f2 dz  = (f2)(A.w) - cz23;
                    const f2 dot = (f2)(A.x) * cnx23 + ((f2)(A.y) * cny23 + (f2)(A.z) * cnz23);
                    f2 c = __builtin_elementwise_max(dot, (f2)(0.f));
                    c = __builtin_elementwise_min(c, (f2)(1.f));
                    f2 s = c * c;
                    s = s * s; s = s * s; s = s * s;
                    s = s * s; s = s * s; s = s * s;
                    const f2 r   = __builtin_elementwise_max(ic23 * rdz23, (f2)(RCLAMP));
                    const f2 ad  = __builtin_elementwise_abs(dz);
                    const f2 arg = ad * r + lw23;
                    f2 w;
                    w.x = __builtin_amdgcn_exp2f(arg.x);
                    w.y = __builtin_amdgcn_exp2f(arg.y);
                    w *= s;
                    ax23 = (f2)(c0) * w + ax23;
                    ay23 = (f2)(c1) * w + ay23;
                    az23 = (f2)(c2) * w + az23;
                    aw23 += w;
                }
            }
        }
    }

    // ---- epilogue: out = accum_col / max(accum_w, EPS) ----
#pragma unroll
    for (int p = 0; p < PY; ++p) {
        const int gy = by0 + ty * PY + p;
        if (gy < IMG_H) {
            float aw, ax, ay, az;
            if (p == 0)      { aw = aw01.x; ax = ax01.x; ay = ay01.x; az = az01.x; }
            else if (p == 1) { aw = aw01.y; ax = ax01.y; ay = ay01.y; az = az01.y; }
            else if (p == 2) { aw = aw23.x; ax = ax23.x; ay = ay23.x; az = az23.x; }
            else             { aw = aw23.y; ax = ax23.y; ay = ay23.y; az = az23.y; }
            const float inv = __builtin_amdgcn_rcpf(fmaxf(aw, 1e-4f));
            const int o = (gy * IMG_W + gx) * 3;
            out[o + 0] = ax * inv;
            out[o + 1] = ay * inv;
            out[o + 2] = az * inv;
        }
    }
}

extern "C" void kernel_launch(void* const* d_in, const int* in_sizes, int n_in,
                              void* d_out, int out_size, void* d_ws, size_t ws_size,
                              hipStream_t stream) {
    const float* in = (const float*)d_in[0];
    float* out = (float*)d_out;
    dim3 grid(IMG_W / TLX, (IMG_H + TLY - 1) / TLY);   // 60 x 34
    dim3 block(32, 8);
    hipLaunchKernelGGL(bilateral_denoise_kernel, grid, block, 0, stream, in, out);
}